// Round 7
// baseline (796.862 us; speedup 1.0000x reference)
//
#include <hip/hip_runtime.h>
#include <stdint.h>

#define HW 16384
#define CH 512
#define KR 19

typedef float f32x4 __attribute__((ext_vector_type(4)));
typedef _Float16 half8 __attribute__((ext_vector_type(8)));
typedef unsigned short us8 __attribute__((ext_vector_type(8)));

__device__ __forceinline__ unsigned short f2h(float f) {
    union { _Float16 h; unsigned short u; } v; v.h = (_Float16)f; return v.u;
}
__device__ __forceinline__ float h2f(unsigned short u) {
    union { unsigned short u; _Float16 h; } v; v.u = u; return (float)v.h;
}

// async global->LDS 16B: wave-uniform LDS base (HW appends lane*16), per-lane global addr.
// NOTE: C-style casts (not reinterpret_cast) — clang performs addrspacecast only for these.
__device__ __forceinline__ void gll16(const void* g, void* l) {
    __builtin_amdgcn_global_load_lds(
        (const __attribute__((address_space(1))) unsigned int*)g,
        (__attribute__((address_space(3))) unsigned int*)l,
        16, 0, 0);
}

__global__ void ObjectAttentionBlock_1176821039805_kernel() {}

// ---------------- prep: weights fp32->fp16, fused BN constants ----------------
__global__ __launch_bounds__(256) void prep_kernel(
    const float* __restrict__ wp1, const float* __restrict__ wp2, const float* __restrict__ wu,
    unsigned short* __restrict__ wp1h, unsigned short* __restrict__ wp2h, unsigned short* __restrict__ wuh,
    const float* gp1, const float* bp1, const float* mp1, const float* vp1,
    const float* gp2, const float* bp2, const float* mp2, const float* vp2,
    const float* gu,  const float* bu,  const float* mu,  const float* vu,
    float* __restrict__ cons)
{
    int i = blockIdx.x * 256 + threadIdx.x;
    if (i < CH * CH) {
        wp1h[i] = f2h(wp1[i]);
        wp2h[i] = f2h(wp2[i]);
        wuh[i]  = f2h(wu[i]);
    }
    if (i < CH) {
        float s1 = gp1[i] * rsqrtf(vp1[i] + 1e-5f);
        cons[i] = s1;          cons[512 + i]  = bp1[i] - mp1[i] * s1;
        float s2 = gp2[i] * rsqrtf(vp2[i] + 1e-5f);
        cons[1024 + i] = s2;   cons[1536 + i] = bp2[i] - mp2[i] * s2;
        float su = gu[i] * rsqrtf(vu[i] + 1e-5f);
        cons[2048 + i] = su;   cons[2560 + i] = bu[i] - mu[i] * su;
    }
}

// ---------------- x [n][c][hw] fp32 -> xT [n][hw][c] fp16 ----------------
__global__ __launch_bounds__(256) void transpose_kernel(
    const float* __restrict__ x, unsigned short* __restrict__ xT)
{
    __shared__ unsigned short t[64][66];
    const int n  = blockIdx.z;
    const int c0 = blockIdx.y * 64;
    const int m0 = blockIdx.x * 64;
    const int tx = threadIdx.x & 63;
    const int ty = threadIdx.x >> 6;
    const float* xb = x + ((size_t)n * CH + c0) * HW + m0;
    #pragma unroll
    for (int r = 0; r < 16; ++r) {
        int cl = ty * 16 + r;
        t[cl][tx] = f2h(xb[(size_t)cl * HW + tx]);
    }
    __syncthreads();
    unsigned short* xo = xT + ((size_t)n * HW + m0) * CH + c0;
    #pragma unroll
    for (int r = 0; r < 16; ++r) {
        int ml = ty * 16 + r;
        xo[(size_t)ml * CH + tx] = t[tx][ml];
    }
}

// ---------------- proxy-side tiny GEMMs (fp32 vector math) ----------------
__global__ __launch_bounds__(256) void kv1_kernel(
    const float* __restrict__ proxy, const float* __restrict__ wo1, const float* __restrict__ wd,
    const float* go1, const float* bo1, const float* mo1, const float* vo1,
    const float* gd,  const float* bd,  const float* md,  const float* vd,
    float* __restrict__ t1, float* __restrict__ vout)
{
    const int n  = blockIdx.x;
    const int o0 = blockIdx.y * 64;
    const float* px = proxy + (size_t)n * CH * KR;
    for (int idx = threadIdx.x; idx < 64 * KR; idx += 256) {
        int o = o0 + idx / KR;
        int j = idx % KR;
        float a1 = 0.f, a2 = 0.f;
        for (int c = 0; c < CH; ++c) {
            float p = px[c * KR + j];
            a1 += wo1[o * CH + c] * p;
            a2 += wd [o * CH + c] * p;
        }
        float s1 = go1[o] * rsqrtf(vo1[o] + 1e-5f);
        float s2 = gd[o]  * rsqrtf(vd[o]  + 1e-5f);
        t1  [((size_t)n * CH + o) * KR + j] = fmaxf(a1 * s1 + (bo1[o] - mo1[o] * s1), 0.f);
        vout[((size_t)n * CH + o) * KR + j] = fmaxf(a2 * s2 + (bd[o]  - md[o]  * s2), 0.f);
    }
}

__global__ __launch_bounds__(256) void kv2_kernel(
    const float* __restrict__ t1, const float* __restrict__ wo2,
    const float* go2, const float* bo2, const float* mo2, const float* vo2,
    float* __restrict__ kout)
{
    const int n  = blockIdx.x;
    const int o0 = blockIdx.y * 64;
    const float* tb = t1 + (size_t)n * CH * KR;
    for (int idx = threadIdx.x; idx < 64 * KR; idx += 256) {
        int o = o0 + idx / KR;
        int j = idx % KR;
        float a = 0.f;
        for (int c = 0; c < CH; ++c) a += wo2[o * CH + c] * tb[c * KR + j];
        float s = go2[o] * rsqrtf(vo2[o] + 1e-5f);
        kout[((size_t)n * CH + o) * KR + j] = fmaxf(a * s + (bo2[o] - mo2[o] * s), 0.f);
    }
}

// ---------------- pad K^T/V^T to fp16 MFMA operands ----------------
__global__ __launch_bounds__(256) void pad_kernel(
    const float* __restrict__ kbuf, const float* __restrict__ vbuf,
    unsigned short* __restrict__ kt, unsigned short* __restrict__ vt)
{
    int idx = blockIdx.x * 256 + threadIdx.x;      // < 8*128*512 = 524288
    int n = idx >> 16, rem = idx & 65535;
    int j = rem >> 9, c = rem & 511;
    kt[idx] = (j < KR) ? f2h(kbuf[((size_t)(n * CH + c)) * KR + j]) : (unsigned short)0;
    int c2 = rem >> 7, j2 = rem & 127;
    vt[idx] = (j2 < KR) ? f2h(vbuf[((size_t)(n * CH + c2)) * KR + j2]) : (unsigned short)0;
}

// ---------------- NT GEMM (f16 MFMA, global_load_lds staging) ----------------
// D[i][j] = sum_k A[i][k]*W[j][k];  A:[M][KEL] fp16, W:[*][KEL] fp16 (+wstride/batch)
// MODE 0: fp16 D -> out[i*NOUT+j] (BN+ReLU if BN)
// MODE 1: fp32 NCHW transposed (final)
// MODE 2: fp32 D -> out[i*NOUT+j] (raw)
template<int MODE, int KTILES, int NOUT, int BN>
__global__ __launch_bounds__(256) void gemm_nt(
    const unsigned short* __restrict__ A,
    const unsigned short* __restrict__ Wg, int wstride,
    const float* __restrict__ sc, const float* __restrict__ sh,
    void* __restrict__ outp)
{
    __shared__ __align__(16) char lds_raw[64 * 132 * 4];   // 33792 B
    unsigned short* stage = (unsigned short*)lds_raw;      // A bytes [0,16384), W [16384,32768)
    float (*epi)[132] = (float (*)[132])lds_raw;

    const int KEL  = KTILES * 64;
    const int tid  = threadIdx.x;
    const int lane = tid & 63;
    const int wave = tid >> 6;
    const int wm = (tid >> 7) & 1;
    const int wn = (tid >> 6) & 1;
    const int i0 = blockIdx.x * 128;
    const int j0 = blockIdx.y * 128;
    const unsigned short* W = Wg + (size_t)(i0 >> 14) * wstride;

    // staging: 8-row groups; row&7 == lane>>3, so source-chunk pre-swizzle is lane-only.
    // LDS stays LINEAR; stored[r][slot s] = global chunk s^(r&7) -> swizzled reads unchanged.
    const int lrow = lane >> 3;                         // row within 8-row group
    const int lsw  = ((lane & 7) ^ (lane >> 3)) * 16;   // byte offset within 128B k-slice

    const f32x4 zero = {0.f, 0.f, 0.f, 0.f};
    f32x4 acc[4][4];
    #pragma unroll
    for (int i = 0; i < 4; ++i)
        #pragma unroll
        for (int j = 0; j < 4; ++j) acc[i][j] = zero;

    const int arow = wm * 64 + (lane & 15);
    const int brow = wn * 64 + (lane & 15);
    const int kch  = lane >> 4;

    for (int kk = 0; kk < KTILES; ++kk) {
        __syncthreads();                            // LDS free (prev compute done)
        #pragma unroll
        for (int q = 0; q < 4; ++q) {
            int r0 = wave * 32 + q * 8;             // wave-uniform base row
            gll16((const char*)A + ((size_t)(i0 + r0 + lrow) * KEL + kk * 64) * 2 + lsw,
                  (char*)lds_raw + r0 * 128);
            gll16((const char*)W + ((size_t)(j0 + r0 + lrow) * KEL + kk * 64) * 2 + lsw,
                  (char*)lds_raw + 16384 + r0 * 128);
        }
        __syncthreads();                            // drains vmcnt before barrier
        #pragma unroll
        for (int s = 0; s < 2; ++s) {
            half8 af[4], bw[4];
            #pragma unroll
            for (int t = 0; t < 4; ++t) {
                int ra = arow + t * 16;
                af[t] = *(const half8*)(stage + ra * 64 + (((s * 4 + kch) ^ (ra & 7)) << 3));
                int rb = brow + t * 16;
                bw[t] = *(const half8*)(stage + 8192 + rb * 64 + (((s * 4 + kch) ^ (rb & 7)) << 3));
            }
            #pragma unroll
            for (int i = 0; i < 4; ++i)
                #pragma unroll
                for (int j = 0; j < 4; ++j)
                    acc[i][j] = __builtin_amdgcn_mfma_f32_16x16x32_f16(af[i], bw[j], acc[i][j], 0, 0, 0);
        }
    }

    float scv[4], shv[4];
    #pragma unroll
    for (int j = 0; j < 4; ++j) {
        int gj = j0 + wn * 64 + j * 16 + (lane & 15);
        scv[j] = BN ? sc[gj] : 1.0f;
        shv[j] = BN ? sh[gj] : 0.0f;
    }

    if (MODE == 0) {
        unsigned short* op = (unsigned short*)outp;
        #pragma unroll
        for (int i = 0; i < 4; ++i) {
            int gi = i0 + wm * 64 + i * 16 + (lane >> 4) * 4;
            #pragma unroll
            for (int j = 0; j < 4; ++j) {
                int gj = j0 + wn * 64 + j * 16 + (lane & 15);
                #pragma unroll
                for (int r = 0; r < 4; ++r) {
                    float vv = acc[i][j][r];
                    if (BN) vv = fmaxf(vv * scv[j] + shv[j], 0.f);
                    op[(size_t)(gi + r) * NOUT + gj] = f2h(vv);
                }
            }
        }
    } else if (MODE == 2) {
        float* op = (float*)outp;
        #pragma unroll
        for (int i = 0; i < 4; ++i) {
            int gi = i0 + wm * 64 + i * 16 + (lane >> 4) * 4;
            #pragma unroll
            for (int j = 0; j < 4; ++j) {
                int gj = j0 + wn * 64 + j * 16 + (lane & 15);
                #pragma unroll
                for (int r = 0; r < 4; ++r)
                    op[(size_t)(gi + r) * NOUT + gj] = acc[i][j][r];
            }
        }
    } else {
        float* op = (float*)outp;
        const int n  = i0 >> 14;
        const int mb = i0 & (HW - 1);
        #pragma unroll
        for (int h = 0; h < 2; ++h) {
            __syncthreads();
            if (wn == h) {
                #pragma unroll
                for (int j = 0; j < 4; ++j) {
                    int ljh = j * 16 + (lane & 15);
                    #pragma unroll
                    for (int i = 0; i < 4; ++i) {
                        int li = wm * 64 + i * 16 + (lane >> 4) * 4;
                        f32x4 vv;
                        #pragma unroll
                        for (int r = 0; r < 4; ++r)
                            vv[r] = fmaxf(acc[i][j][r] * scv[j] + shv[j], 0.f);
                        *(f32x4*)&epi[ljh][li] = vv;
                    }
                }
            }
            __syncthreads();
            #pragma unroll
            for (int q = 0; q < 8; ++q) {
                int idx = q * 256 + tid;
                int ch = idx >> 5, chunk = idx & 31;
                f32x4 v = *(const f32x4*)&epi[ch][chunk * 4];
                size_t base = ((size_t)(n * 512 + j0 + h * 64 + ch) << 14) + mb + chunk * 4;
                op[base] = v[0]; op[base + 1] = v[1]; op[base + 2] = v[2]; op[base + 3] = v[3];
            }
        }
    }
}

// ---------------- softmax over 19 of 128 cols; fp16 att with zero pad ----------------
__global__ __launch_bounds__(256) void softmax_kernel(
    const float* __restrict__ sim, unsigned short* __restrict__ att)
{
    const size_t row = (size_t)blockIdx.x * 256 + threadIdx.x;
    const float* s = sim + row * 128;
    unsigned short* a = att + row * 128;
    const float scale = 0.044194173824159216f;   // 512^-0.5
    float v[KR];
    float mx = -1e30f;
    #pragma unroll
    for (int j = 0; j < KR; ++j) { v[j] = s[j] * scale; mx = fmaxf(mx, v[j]); }
    float ssum = 0.f;
    #pragma unroll
    for (int j = 0; j < KR; ++j) { v[j] = __expf(v[j] - mx); ssum += v[j]; }
    const float inv = 1.0f / ssum;
    us8 o0, o1, o2;
    const us8 zz = {0, 0, 0, 0, 0, 0, 0, 0};
    #pragma unroll
    for (int e = 0; e < 8; ++e) { o0[e] = f2h(v[e] * inv); o1[e] = f2h(v[8 + e] * inv); }
    o2 = zz;
    o2[0] = f2h(v[16] * inv); o2[1] = f2h(v[17] * inv); o2[2] = f2h(v[18] * inv);
    *(us8*)(a) = o0;
    *(us8*)(a + 8) = o1;
    *(us8*)(a + 16) = o2;
    #pragma unroll
    for (int q = 3; q < 16; ++q) *(us8*)(a + q * 8) = zz;
}

extern "C" void kernel_launch(void* const* d_in, const int* in_sizes, int n_in,
                              void* d_out, int out_size, void* d_ws, size_t ws_size,
                              hipStream_t stream)
{
    const float* x     = (const float*)d_in[0];
    const float* proxy = (const float*)d_in[1];
    const float* wp1   = (const float*)d_in[2];
    const float* wp2   = (const float*)d_in[3];
    const float* wo1   = (const float*)d_in[4];
    const float* wo2   = (const float*)d_in[5];
    const float* wd    = (const float*)d_in[6];
    const float* wu    = (const float*)d_in[7];
    const float* gp1 = (const float*)d_in[8],  *bp1 = (const float*)d_in[9];
    const float* mp1 = (const float*)d_in[10], *vp1 = (const float*)d_in[11];
    const float* gp2 = (const float*)d_in[12], *bp2 = (const float*)d_in[13];
    const float* mp2 = (const float*)d_in[14], *vp2 = (const float*)d_in[15];
    const float* go1 = (const float*)d_in[16], *bo1 = (const float*)d_in[17];
    const float* mo1 = (const float*)d_in[18], *vo1 = (const float*)d_in[19];
    const float* go2 = (const float*)d_in[20], *bo2 = (const float*)d_in[21];
    const float* mo2 = (const float*)d_in[22], *vo2 = (const float*)d_in[23];
    const float* gd  = (const float*)d_in[24], *bd  = (const float*)d_in[25];
    const float* md  = (const float*)d_in[26], *vd  = (const float*)d_in[27];
    const float* gu  = (const float*)d_in[28], *bu  = (const float*)d_in[29];
    const float* mu  = (const float*)d_in[30], *vu  = (const float*)d_in[31];

    char* ws = (char*)d_ws;
    unsigned short* r0   = (unsigned short*)ws;               // 134 MB: xT -> q2T -> ctxT (fp16)
    unsigned short* wp1h = (unsigned short*)(ws + 134217728);
    unsigned short* wp2h = wp1h + 262144;
    unsigned short* wuh  = wp2h + 262144;
    float* t1   = (float*)(wuh + 262144);
    float* kbuf = t1 + 8 * CH * KR;
    float* vbuf = kbuf + 8 * CH * KR;
    float* cons = vbuf + 8 * CH * KR;

    float* outf = (float*)d_out;                              // 268 MB fp32 output
    unsigned short* outh = (unsigned short*)d_out;
    unsigned short* q1T   = outh;                             // [0, 67108864) fp16
    float*          simb  = outf + 33554432;                  // fp32 [131072][128]
    unsigned short* attb  = outh + 100663296;                 // fp16 [131072][128]
    unsigned short* ktb   = outh + 117440512;                 // fp16 [8][128][512]
    unsigned short* vtb   = outh + 117964800;                 // fp16 [8][512][128]

    prep_kernel<<<1024, 256, 0, stream>>>(wp1, wp2, wu, wp1h, wp2h, wuh,
        gp1, bp1, mp1, vp1, gp2, bp2, mp2, vp2, gu, bu, mu, vu, cons);
    transpose_kernel<<<dim3(256, 8, 8), 256, 0, stream>>>(x, r0);
    kv1_kernel<<<dim3(8, 8), 256, 0, stream>>>(proxy, wo1, wd,
        go1, bo1, mo1, vo1, gd, bd, md, vd, t1, vbuf);
    kv2_kernel<<<dim3(8, 8), 256, 0, stream>>>(t1, wo2, go2, bo2, mo2, vo2, kbuf);

    // q1T = bn_relu(xT wp1^T) -> d_out low half
    gemm_nt<0, 8, 512, 1><<<dim3(1024, 4), 256, 0, stream>>>(r0, wp1h, 0, cons, cons + 512, q1T);
    // q2T = bn_relu(q1T wp2^T) -> r0
    gemm_nt<0, 8, 512, 1><<<dim3(1024, 4), 256, 0, stream>>>(q1T, wp2h, 0, cons + 1024, cons + 1536, r0);

    // padded KT/VT in d_out upper region
    pad_kernel<<<2048, 256, 0, stream>>>(kbuf, vbuf, ktb, vtb);
    // sim = q2T @ KT^T (per-batch KT), fp32 [131072][128]
    gemm_nt<2, 8, 128, 0><<<dim3(1024, 1), 256, 0, stream>>>(r0, ktb, 65536, cons, cons, simb);
    // att = softmax(sim * kc^-0.5), fp16, zero-padded
    softmax_kernel<<<512, 256, 0, stream>>>(simb, attb);
    // ctx = att @ VT^T (per-batch VT) -> r0 (q2T dead)
    gemm_nt<0, 2, 512, 0><<<dim3(1024, 4), 256, 0, stream>>>(attb, vtb, 65536, cons, cons, r0);

    // out = bn_relu(wu ctx) -> d_out fp32 NCHW (overwrites all scratch last)
    gemm_nt<1, 8, 512, 1><<<dim3(1024, 4), 256, 0, stream>>>(r0, wuh, 0, cons + 2048, cons + 2560, outf);
}

// Round 8
// 735.386 us; speedup vs baseline: 1.0836x; 1.0836x over previous
//
#include <hip/hip_runtime.h>
#include <stdint.h>

#define HW 16384
#define CH 512
#define KR 19

typedef float f32x4 __attribute__((ext_vector_type(4)));
typedef _Float16 half8 __attribute__((ext_vector_type(8)));
typedef unsigned short us8 __attribute__((ext_vector_type(8)));
typedef unsigned short us4 __attribute__((ext_vector_type(4)));

__device__ __forceinline__ unsigned short f2h(float f) {
    union { _Float16 h; unsigned short u; } v; v.h = (_Float16)f; return v.u;
}
__device__ __forceinline__ float h2f(unsigned short u) {
    union { unsigned short u; _Float16 h; } v; v.u = u; return (float)v.h;
}

__global__ void ObjectAttentionBlock_1176821039805_kernel() {}

// ---------------- prep: weights fp32->fp16, fused BN constants ----------------
__global__ __launch_bounds__(256) void prep_kernel(
    const float* __restrict__ wp1, const float* __restrict__ wp2, const float* __restrict__ wu,
    unsigned short* __restrict__ wp1h, unsigned short* __restrict__ wp2h, unsigned short* __restrict__ wuh,
    const float* gp1, const float* bp1, const float* mp1, const float* vp1,
    const float* gp2, const float* bp2, const float* mp2, const float* vp2,
    const float* gu,  const float* bu,  const float* mu,  const float* vu,
    float* __restrict__ cons)
{
    int i = blockIdx.x * 256 + threadIdx.x;
    if (i < CH * CH) {
        wp1h[i] = f2h(wp1[i]);
        wp2h[i] = f2h(wp2[i]);
        wuh[i]  = f2h(wu[i]);
    }
    if (i < CH) {
        float s1 = gp1[i] * rsqrtf(vp1[i] + 1e-5f);
        cons[i] = s1;          cons[512 + i]  = bp1[i] - mp1[i] * s1;
        float s2 = gp2[i] * rsqrtf(vp2[i] + 1e-5f);
        cons[1024 + i] = s2;   cons[1536 + i] = bp2[i] - mp2[i] * s2;
        float su = gu[i] * rsqrtf(vu[i] + 1e-5f);
        cons[2048 + i] = su;   cons[2560 + i] = bu[i] - mu[i] * su;
    }
}

// ---------------- x [n][c][hw] fp32 -> xT [n][hw][c] fp16 ----------------
__global__ __launch_bounds__(256) void transpose_kernel(
    const float* __restrict__ x, unsigned short* __restrict__ xT)
{
    __shared__ unsigned short t[64][66];
    const int n  = blockIdx.z;
    const int c0 = blockIdx.y * 64;
    const int m0 = blockIdx.x * 64;
    const int tx = threadIdx.x & 63;
    const int ty = threadIdx.x >> 6;
    const float* xb = x + ((size_t)n * CH + c0) * HW + m0;
    #pragma unroll
    for (int r = 0; r < 16; ++r) {
        int cl = ty * 16 + r;
        t[cl][tx] = f2h(xb[(size_t)cl * HW + tx]);
    }
    __syncthreads();
    unsigned short* xo = xT + ((size_t)n * HW + m0) * CH + c0;
    #pragma unroll
    for (int r = 0; r < 16; ++r) {
        int ml = ty * 16 + r;
        xo[(size_t)ml * CH + tx] = t[tx][ml];
    }
}

// ---------------- proxy-side tiny GEMMs (fp32 vector math) ----------------
__global__ __launch_bounds__(256) void kv1_kernel(
    const float* __restrict__ proxy, const float* __restrict__ wo1, const float* __restrict__ wd,
    const float* go1, const float* bo1, const float* mo1, const float* vo1,
    const float* gd,  const float* bd,  const float* md,  const float* vd,
    float* __restrict__ t1, float* __restrict__ vout)
{
    const int n  = blockIdx.x;
    const int o0 = blockIdx.y * 64;
    const float* px = proxy + (size_t)n * CH * KR;
    for (int idx = threadIdx.x; idx < 64 * KR; idx += 256) {
        int o = o0 + idx / KR;
        int j = idx % KR;
        float a1 = 0.f, a2 = 0.f;
        for (int c = 0; c < CH; ++c) {
            float p = px[c * KR + j];
            a1 += wo1[o * CH + c] * p;
            a2 += wd [o * CH + c] * p;
        }
        float s1 = go1[o] * rsqrtf(vo1[o] + 1e-5f);
        float s2 = gd[o]  * rsqrtf(vd[o]  + 1e-5f);
        t1  [((size_t)n * CH + o) * KR + j] = fmaxf(a1 * s1 + (bo1[o] - mo1[o] * s1), 0.f);
        vout[((size_t)n * CH + o) * KR + j] = fmaxf(a2 * s2 + (bd[o]  - md[o]  * s2), 0.f);
    }
}

__global__ __launch_bounds__(256) void kv2_kernel(
    const float* __restrict__ t1, const float* __restrict__ wo2,
    const float* go2, const float* bo2, const float* mo2, const float* vo2,
    float* __restrict__ kout)
{
    const int n  = blockIdx.x;
    const int o0 = blockIdx.y * 64;
    const float* tb = t1 + (size_t)n * CH * KR;
    for (int idx = threadIdx.x; idx < 64 * KR; idx += 256) {
        int o = o0 + idx / KR;
        int j = idx % KR;
        float a = 0.f;
        for (int c = 0; c < CH; ++c) a += wo2[o * CH + c] * tb[c * KR + j];
        float s = go2[o] * rsqrtf(vo2[o] + 1e-5f);
        kout[((size_t)n * CH + o) * KR + j] = fmaxf(a * s + (bo2[o] - mo2[o] * s), 0.f);
    }
}

// ---------------- pad K^T/V^T to fp16 MFMA operands ----------------
// KT[n][j][c] (j<19 else 0), [8][128][512];  VT[n][c][j] (j<19 else 0), [8][512][128]
__global__ __launch_bounds__(256) void pad_kernel(
    const float* __restrict__ kbuf, const float* __restrict__ vbuf,
    unsigned short* __restrict__ kt, unsigned short* __restrict__ vt)
{
    int idx = blockIdx.x * 256 + threadIdx.x;      // < 524288
    int n = idx >> 16, rem = idx & 65535;
    int j = rem >> 9, c = rem & 511;
    kt[idx] = (j < KR) ? f2h(kbuf[((size_t)(n * CH + c)) * KR + j]) : (unsigned short)0;
    int c2 = rem >> 7, j2 = rem & 127;
    vt[idx] = (j2 < KR) ? f2h(vbuf[((size_t)(n * CH + c2)) * KR + j2]) : (unsigned short)0;
}

// ---------------- NT GEMM (f16 MFMA, reg-staged prefetch, XCD-chunked swizzle) ----------------
// D[i][j] = sum_k A[i][k]*W[j][k];  A:[131072][512] fp16, W:[512][512] fp16.
// MODE 0: fp16 D -> out[i*512+j] (BN+ReLU if BN); MODE 1: fp32 NCHW transposed.
// grid = 4096 linear; swizzle maps 512-block chunks to XCDs so the 4 j-blocks
// sharing an A-panel are dispatch-adjacent (same XCD L2).
template<int MODE, int BN>
__global__ __launch_bounds__(256) void gemm_nt(
    const unsigned short* __restrict__ A,
    const unsigned short* __restrict__ W,
    const float* __restrict__ sc, const float* __restrict__ sh,
    void* __restrict__ outp)
{
    __shared__ __align__(16) char lds_raw[64 * 132 * 4];   // 33792 B
    unsigned short* stage = (unsigned short*)lds_raw;
    float (*epi)[132] = (float (*)[132])lds_raw;

    const int tid  = threadIdx.x;
    const int lane = tid & 63;
    const int wm = (tid >> 7) & 1;
    const int wn = (tid >> 6) & 1;
    const int id  = blockIdx.x;
    const int swz = (id & 7) * 512 + (id >> 3);            // bijective (4096 % 8 == 0)
    const int i0 = (swz >> 2) << 7;
    const int j0 = (swz & 3) << 7;

    size_t gA[4], gW[4];
    int ldso[4];
    #pragma unroll
    for (int q = 0; q < 4; ++q) {
        int ca = q * 256 + tid;
        int r = ca >> 3, p = ca & 7;
        gA[q] = (size_t)(i0 + r) * 512 + p * 8;
        gW[q] = (size_t)(j0 + r) * 512 + p * 8;
        ldso[q] = r * 64 + ((p ^ (r & 7)) << 3);
    }

    us8 va[4], vb[4];
    #pragma unroll
    for (int q = 0; q < 4; ++q) {
        va[q] = *(const us8*)(A + gA[q]);
        vb[q] = *(const us8*)(W + gW[q]);
    }

    f32x4 acc[4][4];
    #pragma unroll
    for (int i = 0; i < 4; ++i)
        #pragma unroll
        for (int j = 0; j < 4; ++j) acc[i][j] = (f32x4){0.f, 0.f, 0.f, 0.f};

    const int arow = wm * 64 + (lane & 15);
    const int brow = wn * 64 + (lane & 15);
    const int kch  = lane >> 4;

    for (int kk = 0; kk < 8; ++kk) {
        __syncthreads();
        #pragma unroll
        for (int q = 0; q < 4; ++q) {
            *(us8*)(stage + ldso[q]) = va[q];
            *(us8*)(stage + 8192 + ldso[q]) = vb[q];
        }
        __syncthreads();
        if (kk < 7) {
            #pragma unroll
            for (int q = 0; q < 4; ++q) {
                va[q] = *(const us8*)(A + gA[q] + (kk + 1) * 64);
                vb[q] = *(const us8*)(W + gW[q] + (kk + 1) * 64);
            }
        }
        #pragma unroll
        for (int s = 0; s < 2; ++s) {
            half8 af[4], bw[4];
            #pragma unroll
            for (int t = 0; t < 4; ++t) {
                int ra = arow + t * 16;
                af[t] = *(const half8*)(stage + ra * 64 + (((s * 4 + kch) ^ (ra & 7)) << 3));
                int rb = brow + t * 16;
                bw[t] = *(const half8*)(stage + 8192 + rb * 64 + (((s * 4 + kch) ^ (rb & 7)) << 3));
            }
            #pragma unroll
            for (int i = 0; i < 4; ++i)
                #pragma unroll
                for (int j = 0; j < 4; ++j)
                    acc[i][j] = __builtin_amdgcn_mfma_f32_16x16x32_f16(af[i], bw[j], acc[i][j], 0, 0, 0);
        }
    }

    float scv[4], shv[4];
    #pragma unroll
    for (int j = 0; j < 4; ++j) {
        int gj = j0 + wn * 64 + j * 16 + (lane & 15);
        scv[j] = BN ? sc[gj] : 1.0f;
        shv[j] = BN ? sh[gj] : 0.0f;
    }

    if (MODE == 0) {
        unsigned short* op = (unsigned short*)outp;
        #pragma unroll
        for (int i = 0; i < 4; ++i) {
            int gi = i0 + wm * 64 + i * 16 + (lane >> 4) * 4;
            #pragma unroll
            for (int j = 0; j < 4; ++j) {
                int gj = j0 + wn * 64 + j * 16 + (lane & 15);
                #pragma unroll
                for (int r = 0; r < 4; ++r) {
                    float vv = acc[i][j][r];
                    if (BN) vv = fmaxf(vv * scv[j] + shv[j], 0.f);
                    op[(size_t)(gi + r) * 512 + gj] = f2h(vv);
                }
            }
        }
    } else {
        float* op = (float*)outp;
        const int n  = i0 >> 14;
        const int mb = i0 & (HW - 1);
        #pragma unroll
        for (int h = 0; h < 2; ++h) {
            __syncthreads();
            if (wn == h) {
                #pragma unroll
                for (int j = 0; j < 4; ++j) {
                    int ljh = j * 16 + (lane & 15);
                    #pragma unroll
                    for (int i = 0; i < 4; ++i) {
                        int li = wm * 64 + i * 16 + (lane >> 4) * 4;
                        f32x4 vv;
                        #pragma unroll
                        for (int r = 0; r < 4; ++r)
                            vv[r] = fmaxf(acc[i][j][r] * scv[j] + shv[j], 0.f);
                        *(f32x4*)&epi[ljh][li] = vv;
                    }
                }
            }
            __syncthreads();
            #pragma unroll
            for (int q = 0; q < 8; ++q) {
                int idx = q * 256 + tid;
                int ch = idx >> 5, chunk = idx & 31;
                f32x4 v = *(const f32x4*)&epi[ch][chunk * 4];
                size_t base = ((size_t)(n * 512 + j0 + h * 64 + ch) << 14) + mb + chunk * 4;
                op[base] = v[0]; op[base + 1] = v[1]; op[base + 2] = v[2]; op[base + 3] = v[3];
            }
        }
    }
}

// ---------------- fused attention: sim (MFMA) + softmax (in-reg) + ctx (MFMA) ----------------
// Per block: 128 rows. Reads q2 rows once, writes ctx rows once (same buffer, own rows).
__global__ __launch_bounds__(256) void attn_fused(
    const unsigned short* __restrict__ q2,   // [131072][512] fp16
    const unsigned short* __restrict__ ktg,  // [8][128][512] fp16 (rows>=19 zero)
    const unsigned short* __restrict__ vtg,  // [8][512][128] fp16 (cols>=19 zero)
    unsigned short* __restrict__ ctx)        // [131072][512] fp16 (may alias q2; per-block rows)
{
    __shared__ __align__(16) char lds[47104];
    unsigned short* stage = (unsigned short*)lds;            // stage1: A us[0,8192), B us[8192,10240)
    unsigned short* vt_l  = (unsigned short*)lds;            // stage3: [512][36] us (reuses stage)
    unsigned short* att_l = (unsigned short*)(lds + 36864);  // [128][40] us

    const int tid  = threadIdx.x;
    const int lane = tid & 63;
    const int w    = tid >> 6;
    const int i0   = blockIdx.x * 128;
    const int n    = blockIdx.x >> 7;
    const unsigned short* KT = ktg + n * 65536;
    const unsigned short* VT = vtg + n * 65536;

    // ---- stage 1: sim[128][32] = q2[i0..+128][:] x KT[0..32][:]^T ----
    size_t gA[4]; int loA[4];
    #pragma unroll
    for (int q = 0; q < 4; ++q) {
        int ca = q * 256 + tid;
        int r = ca >> 3, p = ca & 7;
        gA[q] = (size_t)(i0 + r) * 512 + p * 8;
        loA[q] = r * 64 + ((p ^ (r & 7)) << 3);
    }
    const int rB = tid >> 3, pB = tid & 7;
    const size_t gB = (size_t)rB * 512 + pB * 8;
    const int loB = 8192 + rB * 64 + ((pB ^ (rB & 7)) << 3);

    us8 va[4], vbk;
    #pragma unroll
    for (int q = 0; q < 4; ++q) va[q] = *(const us8*)(q2 + gA[q]);
    vbk = *(const us8*)(KT + gB);

    f32x4 acc[2][2];
    #pragma unroll
    for (int i = 0; i < 2; ++i)
        #pragma unroll
        for (int j = 0; j < 2; ++j) acc[i][j] = (f32x4){0.f, 0.f, 0.f, 0.f};

    const int kch = lane >> 4;
    for (int kk = 0; kk < 8; ++kk) {
        __syncthreads();
        #pragma unroll
        for (int q = 0; q < 4; ++q) *(us8*)(stage + loA[q]) = va[q];
        *(us8*)(stage + loB) = vbk;
        __syncthreads();
        if (kk < 7) {
            #pragma unroll
            for (int q = 0; q < 4; ++q) va[q] = *(const us8*)(q2 + gA[q] + (kk + 1) * 64);
            vbk = *(const us8*)(KT + gB + (kk + 1) * 64);
        }
        #pragma unroll
        for (int s = 0; s < 2; ++s) {
            half8 af[2], bf[2];
            #pragma unroll
            for (int i = 0; i < 2; ++i) {
                int ra = w * 32 + i * 16 + (lane & 15);
                af[i] = *(const half8*)(stage + ra * 64 + (((s * 4 + kch) ^ (ra & 7)) << 3));
            }
            #pragma unroll
            for (int t = 0; t < 2; ++t) {
                int rb = t * 16 + (lane & 15);
                bf[t] = *(const half8*)(stage + 8192 + rb * 64 + (((s * 4 + kch) ^ (rb & 7)) << 3));
            }
            #pragma unroll
            for (int i = 0; i < 2; ++i)
                #pragma unroll
                for (int j = 0; j < 2; ++j)
                    acc[i][j] = __builtin_amdgcn_mfma_f32_16x16x32_f16(af[i], bf[j], acc[i][j], 0, 0, 0);
        }
    }

    // ---- stage 2: row softmax over 19 valid cols (cols 0..15 in frag0, 16..18 in frag1) ----
    const float scale = 0.044194173824159216f;   // 512^-0.5
    const bool v1 = (lane & 15) < 3;
    unsigned short a16[2][4][2];
    #pragma unroll
    for (int i = 0; i < 2; ++i) {
        #pragma unroll
        for (int r = 0; r < 4; ++r) {
            float s0 = acc[i][0][r] * scale;
            float s1v = acc[i][1][r] * scale;
            float m = v1 ? fmaxf(s0, s1v) : s0;
            m = fmaxf(m, __shfl_xor(m, 1));
            m = fmaxf(m, __shfl_xor(m, 2));
            m = fmaxf(m, __shfl_xor(m, 4));
            m = fmaxf(m, __shfl_xor(m, 8));
            float a0 = __expf(s0 - m);
            float a1 = v1 ? __expf(s1v - m) : 0.f;
            float sm = a0 + a1;
            sm += __shfl_xor(sm, 1);
            sm += __shfl_xor(sm, 2);
            sm += __shfl_xor(sm, 4);
            sm += __shfl_xor(sm, 8);
            float inv = 1.0f / sm;
            a16[i][r][0] = f2h(a0 * inv);
            a16[i][r][1] = f2h(a1 * inv);
        }
    }
    // write att tile to att_l [128][40] (disjoint from stage region)
    #pragma unroll
    for (int i = 0; i < 2; ++i)
        #pragma unroll
        for (int r = 0; r < 4; ++r) {
            int R = w * 32 + i * 16 + (lane >> 4) * 4 + r;
            att_l[R * 40 + (lane & 15)]      = a16[i][r][0];
            att_l[R * 40 + 16 + (lane & 15)] = a16[i][r][1];
        }
    __syncthreads();   // stage-1 LDS reads done everywhere; att_l complete

    // ---- stage VT [512][128]->[512][36] (cols 0..31) into vt_l (overwrites stage) ----
    #pragma unroll
    for (int q = 0; q < 8; ++q) {
        int id = q * 256 + tid;
        int c = id >> 2, part = id & 3;
        us8 v = *(const us8*)(VT + (size_t)c * 128 + part * 8);
        *(us4*)(vt_l + c * 36 + part * 8)     = (us4){v[0], v[1], v[2], v[3]};
        *(us4*)(vt_l + c * 36 + part * 8 + 4) = (us4){v[4], v[5], v[6], v[7]};
    }
    __syncthreads();

    // ---- stage 3: ctx[128][512] = att[128][32] x VT[512][32]^T (K=32, 1 MFMA) ----
    half8 a2[2];
    #pragma unroll
    for (int i = 0; i < 2; ++i) {
        int R = w * 32 + i * 16 + (lane & 15);
        a2[i] = *(const half8*)(att_l + R * 40 + (lane >> 4) * 8);
    }
    #pragma unroll
    for (int jc = 0; jc < 4; ++jc) {
        half8 bf[8];
        #pragma unroll
        for (int t = 0; t < 8; ++t) {
            int c = jc * 128 + t * 16 + (lane & 15);
            const unsigned short* pb = vt_l + c * 36 + (lane >> 4) * 8;
            us4 lo = *(const us4*)(pb);
            us4 hi = *(const us4*)(pb + 4);
            us8 u = {lo[0], lo[1], lo[2], lo[3], hi[0], hi[1], hi[2], hi[3]};
            bf[t] = *(half8*)&u;
        }
        #pragma unroll
        for (int i = 0; i < 2; ++i) {
            #pragma unroll
            for (int t = 0; t < 8; ++t) {
                f32x4 o = __builtin_amdgcn_mfma_f32_16x16x32_f16(
                    a2[i], bf[t], (f32x4){0.f, 0.f, 0.f, 0.f}, 0, 0, 0);
                int col = jc * 128 + t * 16 + (lane & 15);
                int row = i0 + w * 32 + i * 16 + (lane >> 4) * 4;
                #pragma unroll
                for (int r = 0; r < 4; ++r)
                    ctx[(size_t)(row + r) * 512 + col] = f2h(o[r]);
            }
        }
    }
}

extern "C" void kernel_launch(void* const* d_in, const int* in_sizes, int n_in,
                              void* d_out, int out_size, void* d_ws, size_t ws_size,
                              hipStream_t stream)
{
    const float* x     = (const float*)d_in[0];
    const float* proxy = (const float*)d_in[1];
    const float* wp1   = (const float*)d_in[2];
    const float* wp2   = (const float*)d_in[3];
    const float* wo1   = (const float*)d_in[4];
    const float* wo2   = (const float*)d_in[5];
    const float* wd    = (const float*)d_in[6];
    const float* wu    = (const float*)d_in[7];
    const float* gp1 = (const float*)d_in[8],  *bp1 = (const float*)d_in[9];
    const float* mp1 = (const float*)d_in[10], *vp1 = (const float*)d_in[11];
    const float* gp2 = (const float*)d_in[12], *bp2 = (const float*)d_in[13];
    const float* mp2 = (const float*)d_in[14], *vp2 = (const float*)d_in[15];
    const float* go1 = (const float*)d_in[16], *bo1 = (const float*)d_in[17];
    const float* mo1 = (const float*)d_in[18], *vo1 = (const float*)d_in[19];
    const float* go2 = (const float*)d_in[20], *bo2 = (const float*)d_in[21];
    const float* mo2 = (const float*)d_in[22], *vo2 = (const float*)d_in[23];
    const float* gd  = (const float*)d_in[24], *bd  = (const float*)d_in[25];
    const float* md  = (const float*)d_in[26], *vd  = (const float*)d_in[27];
    const float* gu  = (const float*)d_in[28], *bu  = (const float*)d_in[29];
    const float* mu  = (const float*)d_in[30], *vu  = (const float*)d_in[31];

    char* ws = (char*)d_ws;
    unsigned short* r0   = (unsigned short*)ws;               // 134 MB: xT -> q2T -> ctxT (fp16)
    unsigned short* wp1h = (unsigned short*)(ws + 134217728);
    unsigned short* wp2h = wp1h + 262144;
    unsigned short* wuh  = wp2h + 262144;
    float* t1   = (float*)(wuh + 262144);
    float* kbuf = t1 + 8 * CH * KR;
    float* vbuf = kbuf + 8 * CH * KR;
    float* cons = vbuf + 8 * CH * KR;

    float* outf = (float*)d_out;                              // 268 MB fp32 output
    unsigned short* outh = (unsigned short*)d_out;
    unsigned short* q1T = outh;                               // [0, 67108864) fp16
    unsigned short* ktb = outh + 117440512;                   // fp16 [8][128][512]
    unsigned short* vtb = outh + 117964800;                   // fp16 [8][512][128]

    prep_kernel<<<1024, 256, 0, stream>>>(wp1, wp2, wu, wp1h, wp2h, wuh,
        gp1, bp1, mp1, vp1, gp2, bp2, mp2, vp2, gu, bu, mu, vu, cons);
    transpose_kernel<<<dim3(256, 8, 8), 256, 0, stream>>>(x, r0);
    kv1_kernel<<<dim3(8, 8), 256, 0, stream>>>(proxy, wo1, wd,
        go1, bo1, mo1, vo1, gd, bd, md, vd, t1, vbuf);
    kv2_kernel<<<dim3(8, 8), 256, 0, stream>>>(t1, wo2, go2, bo2, mo2, vo2, kbuf);
    pad_kernel<<<2048, 256, 0, stream>>>(kbuf, vbuf, ktb, vtb);

    // q1T = bn_relu(xT wp1^T) -> d_out low half
    gemm_nt<0, 1><<<4096, 256, 0, stream>>>(r0, wp1h, cons, cons + 512, q1T);
    // q2T = bn_relu(q1T wp2^T) -> r0
    gemm_nt<0, 1><<<4096, 256, 0, stream>>>(q1T, wp2h, cons + 1024, cons + 1536, r0);
    // fused attention: r0 (q2T) -> r0 (ctx), per-block row ownership
    attn_fused<<<1024, 256, 0, stream>>>(r0, ktb, vtb, r0);
    // out = bn_relu(wu ctx) -> d_out fp32 NCHW (overwrites all scratch last)
    gemm_nt<1, 1><<<4096, 256, 0, stream>>>(r0, wuh, cons + 2048, cons + 2560, outf);
}

// Round 9
// 707.819 us; speedup vs baseline: 1.1258x; 1.0389x over previous
//
#include <hip/hip_runtime.h>
#include <stdint.h>

#define HW 16384
#define CH 512
#define KR 19

typedef float f32x4 __attribute__((ext_vector_type(4)));
typedef _Float16 half8 __attribute__((ext_vector_type(8)));
typedef unsigned short us8 __attribute__((ext_vector_type(8)));
typedef unsigned short us4 __attribute__((ext_vector_type(4)));

__device__ __forceinline__ unsigned short f2h(float f) {
    union { _Float16 h; unsigned short u; } v; v.h = (_Float16)f; return v.u;
}
__device__ __forceinline__ float h2f(unsigned short u) {
    union { unsigned short u; _Float16 h; } v; v.u = u; return (float)v.h;
}

__device__ __forceinline__ void gll16(const void* g, void* l) {
    __builtin_amdgcn_global_load_lds(
        (const __attribute__((address_space(1))) unsigned int*)g,
        (__attribute__((address_space(3))) unsigned int*)l,
        16, 0, 0);
}

__global__ void ObjectAttentionBlock_1176821039805_kernel() {}

// ---------------- prep: weights fp32->fp16, fused BN constants ----------------
__global__ __launch_bounds__(256) void prep_kernel(
    const float* __restrict__ wp1, const float* __restrict__ wp2, const float* __restrict__ wu,
    unsigned short* __restrict__ wp1h, unsigned short* __restrict__ wp2h, unsigned short* __restrict__ wuh,
    const float* gp1, const float* bp1, const float* mp1, const float* vp1,
    const float* gp2, const float* bp2, const float* mp2, const float* vp2,
    const float* gu,  const float* bu,  const float* mu,  const float* vu,
    float* __restrict__ cons)
{
    int i = blockIdx.x * 256 + threadIdx.x;
    if (i < CH * CH) {
        wp1h[i] = f2h(wp1[i]);
        wp2h[i] = f2h(wp2[i]);
        wuh[i]  = f2h(wu[i]);
    }
    if (i < CH) {
        float s1 = gp1[i] * rsqrtf(vp1[i] + 1e-5f);
        cons[i] = s1;          cons[512 + i]  = bp1[i] - mp1[i] * s1;
        float s2 = gp2[i] * rsqrtf(vp2[i] + 1e-5f);
        cons[1024 + i] = s2;   cons[1536 + i] = bp2[i] - mp2[i] * s2;
        float su = gu[i] * rsqrtf(vu[i] + 1e-5f);
        cons[2048 + i] = su;   cons[2560 + i] = bu[i] - mu[i] * su;
    }
}

// ---------------- x [n][c][hw] fp32 -> xT [n][hw][c] fp16 ----------------
__global__ __launch_bounds__(256) void transpose_kernel(
    const float* __restrict__ x, unsigned short* __restrict__ xT)
{
    __shared__ unsigned short t[64][66];
    const int n  = blockIdx.z;
    const int c0 = blockIdx.y * 64;
    const int m0 = blockIdx.x * 64;
    const int tx = threadIdx.x & 63;
    const int ty = threadIdx.x >> 6;
    const float* xb = x + ((size_t)n * CH + c0) * HW + m0;
    #pragma unroll
    for (int r = 0; r < 16; ++r) {
        int cl = ty * 16 + r;
        t[cl][tx] = f2h(xb[(size_t)cl * HW + tx]);
    }
    __syncthreads();
    unsigned short* xo = xT + ((size_t)n * HW + m0) * CH + c0;
    #pragma unroll
    for (int r = 0; r < 16; ++r) {
        int ml = ty * 16 + r;
        xo[(size_t)ml * CH + tx] = t[tx][ml];
    }
}

// ---------------- proxy-side tiny GEMMs (fp32 vector math) ----------------
__global__ __launch_bounds__(256) void kv1_kernel(
    const float* __restrict__ proxy, const float* __restrict__ wo1, const float* __restrict__ wd,
    const float* go1, const float* bo1, const float* mo1, const float* vo1,
    const float* gd,  const float* bd,  const float* md,  const float* vd,
    float* __restrict__ t1, float* __restrict__ vout)
{
    const int n  = blockIdx.x;
    const int o0 = blockIdx.y * 64;
    const float* px = proxy + (size_t)n * CH * KR;
    for (int idx = threadIdx.x; idx < 64 * KR; idx += 256) {
        int o = o0 + idx / KR;
        int j = idx % KR;
        float a1 = 0.f, a2 = 0.f;
        for (int c = 0; c < CH; ++c) {
            float p = px[c * KR + j];
            a1 += wo1[o * CH + c] * p;
            a2 += wd [o * CH + c] * p;
        }
        float s1 = go1[o] * rsqrtf(vo1[o] + 1e-5f);
        float s2 = gd[o]  * rsqrtf(vd[o]  + 1e-5f);
        t1  [((size_t)n * CH + o) * KR + j] = fmaxf(a1 * s1 + (bo1[o] - mo1[o] * s1), 0.f);
        vout[((size_t)n * CH + o) * KR + j] = fmaxf(a2 * s2 + (bd[o]  - md[o]  * s2), 0.f);
    }
}

__global__ __launch_bounds__(256) void kv2_kernel(
    const float* __restrict__ t1, const float* __restrict__ wo2,
    const float* go2, const float* bo2, const float* mo2, const float* vo2,
    float* __restrict__ kout)
{
    const int n  = blockIdx.x;
    const int o0 = blockIdx.y * 64;
    const float* tb = t1 + (size_t)n * CH * KR;
    for (int idx = threadIdx.x; idx < 64 * KR; idx += 256) {
        int o = o0 + idx / KR;
        int j = idx % KR;
        float a = 0.f;
        for (int c = 0; c < CH; ++c) a += wo2[o * CH + c] * tb[c * KR + j];
        float s = go2[o] * rsqrtf(vo2[o] + 1e-5f);
        kout[((size_t)n * CH + o) * KR + j] = fmaxf(a * s + (bo2[o] - mo2[o] * s), 0.f);
    }
}

// ---------------- pad K^T/V^T to fp16 MFMA operands ----------------
__global__ __launch_bounds__(256) void pad_kernel(
    const float* __restrict__ kbuf, const float* __restrict__ vbuf,
    unsigned short* __restrict__ kt, unsigned short* __restrict__ vt)
{
    int idx = blockIdx.x * 256 + threadIdx.x;      // < 524288
    int n = idx >> 16, rem = idx & 65535;
    int j = rem >> 9, c = rem & 511;
    kt[idx] = (j < KR) ? f2h(kbuf[((size_t)(n * CH + c)) * KR + j]) : (unsigned short)0;
    int c2 = rem >> 7, j2 = rem & 127;
    vt[idx] = (j2 < KR) ? f2h(vbuf[((size_t)(n * CH + c2)) * KR + j2]) : (unsigned short)0;
}

// ---------------- 256x256 NT GEMM, BK=64, dbuf gll staging, counted vmcnt ----------------
// D[i][j] = sum_k A[i][k]*W[j][k];  A:[131072][512] fp16, W:[512][512] fp16, K=512.
// 512 threads = 8 waves (2M x 4N), per-wave out 128x64, acc[8][4] f32x4.
// LDS 128 KB: 2 bufs x (A 32KB + B 32KB). Schedule per K-tile t:
//   vmcnt(8) [t<7, tile t arrived; tile t+1 in flight] -> s_barrier -> 64 MFMA (setprio)
//   -> s_barrier -> stage tile t+2 into buf[t&1] (idle window; race-free).
// MODE 0: fp16 D -> out[i*512+j] (BN+ReLU); MODE 1: fp32 NCHW transposed (BN+ReLU).
template<int MODE, int BN>
__global__ __launch_bounds__(512, 1) void gemm256(
    const unsigned short* __restrict__ A,
    const unsigned short* __restrict__ W,
    const float* __restrict__ sc, const float* __restrict__ sh,
    void* __restrict__ outp)
{
    __shared__ __align__(16) char lds[131072];

    const int tid  = threadIdx.x;
    const int lane = tid & 63;
    const int w    = tid >> 6;
    const int wm   = w >> 2;          // 0..1
    const int wn   = w & 3;           // 0..3
    const int id   = blockIdx.x;
    const int swz  = (id & 7) * 128 + (id >> 3);   // bijective, XCD-chunked
    const int i0   = (swz >> 1) << 8;
    const int j0   = (swz & 1) << 8;

    const int lr = lane >> 3;                      // row within 8-row group
    const int lc = (lane & 7) ^ (lane >> 3);       // pre-swizzled source chunk

    f32x4 acc[8][4];
    #pragma unroll
    for (int i = 0; i < 8; ++i)
        #pragma unroll
        for (int j = 0; j < 4; ++j) acc[i][j] = (f32x4){0.f, 0.f, 0.f, 0.f};

    const int rl  = lane & 15;
    const int kch = lane >> 4;

    // stage tile t into buf[t&1]: 8 gll16/thread (4 A + 4 B)
    auto stage = [&](int t) {
        char* db = lds + (t & 1) * 65536;
        #pragma unroll
        for (int q = 0; q < 4; ++q) {
            int grp = q * 8 + w;
            gll16(A + (size_t)(i0 + grp * 8 + lr) * 512 + t * 64 + lc * 8,
                  db + q * 8192 + w * 1024);
        }
        #pragma unroll
        for (int q = 0; q < 4; ++q) {
            int grp = q * 8 + w;
            gll16(W + (size_t)(j0 + grp * 8 + lr) * 512 + t * 64 + lc * 8,
                  db + 32768 + q * 8192 + w * 1024);
        }
    };

    stage(0);
    stage(1);

    for (int t = 0; t < 8; ++t) {
        if (t < 7) asm volatile("s_waitcnt vmcnt(8)" ::: "memory");
        else       asm volatile("s_waitcnt vmcnt(0)" ::: "memory");
        __builtin_amdgcn_sched_barrier(0);
        __builtin_amdgcn_s_barrier();
        __builtin_amdgcn_sched_barrier(0);

        const unsigned short* db = (const unsigned short*)(lds + (t & 1) * 65536);
        __builtin_amdgcn_s_setprio(1);
        #pragma unroll
        for (int s = 0; s < 2; ++s) {
            half8 af[8], bw[4];
            #pragma unroll
            for (int rf = 0; rf < 8; ++rf) {
                int ra = wm * 128 + rf * 16 + rl;
                af[rf] = *(const half8*)(db + ra * 64 + (((s * 4 + kch) ^ (ra & 7)) << 3));
            }
            #pragma unroll
            for (int cf = 0; cf < 4; ++cf) {
                int rb = wn * 64 + cf * 16 + rl;
                bw[cf] = *(const half8*)(db + 16384 + rb * 64 + (((s * 4 + kch) ^ (rb & 7)) << 3));
            }
            #pragma unroll
            for (int rf = 0; rf < 8; ++rf)
                #pragma unroll
                for (int cf = 0; cf < 4; ++cf)
                    acc[rf][cf] = __builtin_amdgcn_mfma_f32_16x16x32_f16(af[rf], bw[cf], acc[rf][cf], 0, 0, 0);
        }
        __builtin_amdgcn_s_setprio(0);
        __builtin_amdgcn_sched_barrier(0);
        __builtin_amdgcn_s_barrier();
        __builtin_amdgcn_sched_barrier(0);
        if (t < 6) stage(t + 2);
    }

    float scv[4], shv[4];
    #pragma unroll
    for (int cf = 0; cf < 4; ++cf) {
        int gj = j0 + wn * 64 + cf * 16 + rl;
        scv[cf] = BN ? sc[gj] : 1.0f;
        shv[cf] = BN ? sh[gj] : 0.0f;
    }

    if (MODE == 0) {
        unsigned short* op = (unsigned short*)outp;
        #pragma unroll
        for (int rf = 0; rf < 8; ++rf) {
            int gi = i0 + wm * 128 + rf * 16 + (lane >> 4) * 4;
            #pragma unroll
            for (int cf = 0; cf < 4; ++cf) {
                int gj = j0 + wn * 64 + cf * 16 + rl;
                #pragma unroll
                for (int e = 0; e < 4; ++e) {
                    float vv = acc[rf][cf][e];
                    if (BN) vv = fmaxf(vv * scv[cf] + shv[cf], 0.f);
                    op[(size_t)(gi + e) * 512 + gj] = f2h(vv);
                }
            }
        }
    } else {
        float* op = (float*)outp;
        float (*epi)[260] = (float (*)[260])lds;
        const int n  = i0 >> 14;
        const int mb = i0 & (HW - 1);
        const int ch  = tid >> 3;
        const int prt = tid & 7;
        #pragma unroll
        for (int g = 0; g < 4; ++g) {
            __syncthreads();
            if (wn == g) {
                #pragma unroll
                for (int cf = 0; cf < 4; ++cf) {
                    int chl = cf * 16 + rl;
                    #pragma unroll
                    for (int rf = 0; rf < 8; ++rf) {
                        int px = wm * 128 + rf * 16 + (lane >> 4) * 4;
                        f32x4 vv;
                        #pragma unroll
                        for (int e = 0; e < 4; ++e)
                            vv[e] = fmaxf(acc[rf][cf][e] * scv[cf] + shv[cf], 0.f);
                        *(f32x4*)&epi[chl][px] = vv;
                    }
                }
            }
            __syncthreads();
            size_t base = ((size_t)(n * 512 + j0 + g * 64 + ch) << 14) + mb + prt * 32;
            #pragma unroll
            for (int u = 0; u < 8; ++u) {
                f32x4 v = *(const f32x4*)&epi[ch][prt * 32 + u * 4];
                *(f32x4*)&op[base + u * 4] = v;
            }
        }
    }
}

// ---------------- fused attention: sim (MFMA) + softmax (in-reg) + ctx (MFMA) ----------------
__global__ __launch_bounds__(256) void attn_fused(
    const unsigned short* __restrict__ q2,   // [131072][512] fp16
    const unsigned short* __restrict__ ktg,  // [8][128][512] fp16 (rows>=19 zero)
    const unsigned short* __restrict__ vtg,  // [8][512][128] fp16 (cols>=19 zero)
    unsigned short* __restrict__ ctx)        // [131072][512] fp16 (aliases q2; per-block rows)
{
    __shared__ __align__(16) char lds[47104];
    unsigned short* stage = (unsigned short*)lds;
    unsigned short* vt_l  = (unsigned short*)lds;
    unsigned short* att_l = (unsigned short*)(lds + 36864);

    const int tid  = threadIdx.x;
    const int lane = tid & 63;
    const int w    = tid >> 6;
    const int i0   = blockIdx.x * 128;
    const int n    = blockIdx.x >> 7;
    const unsigned short* KT = ktg + n * 65536;
    const unsigned short* VT = vtg + n * 65536;

    size_t gA[4]; int loA[4];
    #pragma unroll
    for (int q = 0; q < 4; ++q) {
        int ca = q * 256 + tid;
        int r = ca >> 3, p = ca & 7;
        gA[q] = (size_t)(i0 + r) * 512 + p * 8;
        loA[q] = r * 64 + ((p ^ (r & 7)) << 3);
    }
    const int rB = tid >> 3, pB = tid & 7;
    const size_t gB = (size_t)rB * 512 + pB * 8;
    const int loB = 8192 + rB * 64 + ((pB ^ (rB & 7)) << 3);

    us8 va[4], vbk;
    #pragma unroll
    for (int q = 0; q < 4; ++q) va[q] = *(const us8*)(q2 + gA[q]);
    vbk = *(const us8*)(KT + gB);

    f32x4 acc[2][2];
    #pragma unroll
    for (int i = 0; i < 2; ++i)
        #pragma unroll
        for (int j = 0; j < 2; ++j) acc[i][j] = (f32x4){0.f, 0.f, 0.f, 0.f};

    const int kch = lane >> 4;
    for (int kk = 0; kk < 8; ++kk) {
        __syncthreads();
        #pragma unroll
        for (int q = 0; q < 4; ++q) *(us8*)(stage + loA[q]) = va[q];
        *(us8*)(stage + loB) = vbk;
        __syncthreads();
        if (kk < 7) {
            #pragma unroll
            for (int q = 0; q < 4; ++q) va[q] = *(const us8*)(q2 + gA[q] + (kk + 1) * 64);
            vbk = *(const us8*)(KT + gB + (kk + 1) * 64);
        }
        #pragma unroll
        for (int s = 0; s < 2; ++s) {
            half8 af[2], bf[2];
            #pragma unroll
            for (int i = 0; i < 2; ++i) {
                int ra = w * 32 + i * 16 + (lane & 15);
                af[i] = *(const half8*)(stage + ra * 64 + (((s * 4 + kch) ^ (ra & 7)) << 3));
            }
            #pragma unroll
            for (int t = 0; t < 2; ++t) {
                int rb = t * 16 + (lane & 15);
                bf[t] = *(const half8*)(stage + 8192 + rb * 64 + (((s * 4 + kch) ^ (rb & 7)) << 3));
            }
            #pragma unroll
            for (int i = 0; i < 2; ++i)
                #pragma unroll
                for (int j = 0; j < 2; ++j)
                    acc[i][j] = __builtin_amdgcn_mfma_f32_16x16x32_f16(af[i], bf[j], acc[i][j], 0, 0, 0);
        }
    }

    const float scale = 0.044194173824159216f;   // 512^-0.5
    const bool v1 = (lane & 15) < 3;
    unsigned short a16[2][4][2];
    #pragma unroll
    for (int i = 0; i < 2; ++i) {
        #pragma unroll
        for (int r = 0; r < 4; ++r) {
            float s0 = acc[i][0][r] * scale;
            float s1v = acc[i][1][r] * scale;
            float m = v1 ? fmaxf(s0, s1v) : s0;
            m = fmaxf(m, __shfl_xor(m, 1));
            m = fmaxf(m, __shfl_xor(m, 2));
            m = fmaxf(m, __shfl_xor(m, 4));
            m = fmaxf(m, __shfl_xor(m, 8));
            float a0 = __expf(s0 - m);
            float a1 = v1 ? __expf(s1v - m) : 0.f;
            float sm = a0 + a1;
            sm += __shfl_xor(sm, 1);
            sm += __shfl_xor(sm, 2);
            sm += __shfl_xor(sm, 4);
            sm += __shfl_xor(sm, 8);
            float inv = 1.0f / sm;
            a16[i][r][0] = f2h(a0 * inv);
            a16[i][r][1] = f2h(a1 * inv);
        }
    }
    #pragma unroll
    for (int i = 0; i < 2; ++i)
        #pragma unroll
        for (int r = 0; r < 4; ++r) {
            int R = w * 32 + i * 16 + (lane >> 4) * 4 + r;
            att_l[R * 40 + (lane & 15)]      = a16[i][r][0];
            att_l[R * 40 + 16 + (lane & 15)] = a16[i][r][1];
        }
    __syncthreads();

    #pragma unroll
    for (int q = 0; q < 8; ++q) {
        int id = q * 256 + tid;
        int c = id >> 2, part = id & 3;
        us8 v = *(const us8*)(VT + (size_t)c * 128 + part * 8);
        *(us4*)(vt_l + c * 36 + part * 8)     = (us4){v[0], v[1], v[2], v[3]};
        *(us4*)(vt_l + c * 36 + part * 8 + 4) = (us4){v[4], v[5], v[6], v[7]};
    }
    __syncthreads();

    half8 a2[2];
    #pragma unroll
    for (int i = 0; i < 2; ++i) {
        int R = w * 32 + i * 16 + (lane & 15);
        a2[i] = *(const half8*)(att_l + R * 40 + (lane >> 4) * 8);
    }
    #pragma unroll
    for (int jc = 0; jc < 4; ++jc) {
        half8 bf[8];
        #pragma unroll
        for (int t = 0; t < 8; ++t) {
            int c = jc * 128 + t * 16 + (lane & 15);
            const unsigned short* pb = vt_l + c * 36 + (lane >> 4) * 8;
            us4 lo = *(const us4*)(pb);
            us4 hi = *(const us4*)(pb + 4);
            us8 u = {lo[0], lo[1], lo[2], lo[3], hi[0], hi[1], hi[2], hi[3]};
            bf[t] = *(half8*)&u;
        }
        #pragma unroll
        for (int i = 0; i < 2; ++i) {
            #pragma unroll
            for (int t = 0; t < 8; ++t) {
                f32x4 o = __builtin_amdgcn_mfma_f32_16x16x32_f16(
                    a2[i], bf[t], (f32x4){0.f, 0.f, 0.f, 0.f}, 0, 0, 0);
                int col = jc * 128 + t * 16 + (lane & 15);
                int row = i0 + w * 32 + i * 16 + (lane >> 4) * 4;
                #pragma unroll
                for (int r = 0; r < 4; ++r)
                    ctx[(size_t)(row + r) * 512 + col] = f2h(o[r]);
            }
        }
    }
}

extern "C" void kernel_launch(void* const* d_in, const int* in_sizes, int n_in,
                              void* d_out, int out_size, void* d_ws, size_t ws_size,
                              hipStream_t stream)
{
    const float* x     = (const float*)d_in[0];
    const float* proxy = (const float*)d_in[1];
    const float* wp1   = (const float*)d_in[2];
    const float* wp2   = (const float*)d_in[3];
    const float* wo1   = (const float*)d_in[4];
    const float* wo2   = (const float*)d_in[5];
    const float* wd    = (const float*)d_in[6];
    const float* wu    = (const float*)d_in[7];
    const float* gp1 = (const float*)d_in[8],  *bp1 = (const float*)d_in[9];
    const float* mp1 = (const float*)d_in[10], *vp1 = (const float*)d_in[11];
    const float* gp2 = (const float*)d_in[12], *bp2 = (const float*)d_in[13];
    const float* mp2 = (const float*)d_in[14], *vp2 = (const float*)d_in[15];
    const float* go1 = (const float*)d_in[16], *bo1 = (const float*)d_in[17];
    const float* mo1 = (const float*)d_in[18], *vo1 = (const float*)d_in[19];
    const float* go2 = (const float*)d_in[20], *bo2 = (const float*)d_in[21];
    const float* mo2 = (const float*)d_in[22], *vo2 = (const float*)d_in[23];
    const float* gd  = (const float*)d_in[24], *bd  = (const float*)d_in[25];
    const float* md  = (const float*)d_in[26], *vd  = (const float*)d_in[27];
    const float* gu  = (const float*)d_in[28], *bu  = (const float*)d_in[29];
    const float* mu  = (const float*)d_in[30], *vu  = (const float*)d_in[31];

    char* ws = (char*)d_ws;
    unsigned short* r0   = (unsigned short*)ws;               // 134 MB: xT -> q2T -> ctxT (fp16)
    unsigned short* wp1h = (unsigned short*)(ws + 134217728);
    unsigned short* wp2h = wp1h + 262144;
    unsigned short* wuh  = wp2h + 262144;
    float* t1   = (float*)(wuh + 262144);
    float* kbuf = t1 + 8 * CH * KR;
    float* vbuf = kbuf + 8 * CH * KR;
    float* cons = vbuf + 8 * CH * KR;

    float* outf = (float*)d_out;                              // 268 MB fp32 output
    unsigned short* outh = (unsigned short*)d_out;
    unsigned short* q1T = outh;                               // [0, 67108864) fp16
    unsigned short* ktb = outh + 117440512;                   // fp16 [8][128][512]
    unsigned short* vtb = outh + 117964800;                   // fp16 [8][512][128]

    prep_kernel<<<1024, 256, 0, stream>>>(wp1, wp2, wu, wp1h, wp2h, wuh,
        gp1, bp1, mp1, vp1, gp2, bp2, mp2, vp2, gu, bu, mu, vu, cons);
    transpose_kernel<<<dim3(256, 8, 8), 256, 0, stream>>>(x, r0);
    kv1_kernel<<<dim3(8, 8), 256, 0, stream>>>(proxy, wo1, wd,
        go1, bo1, mo1, vo1, gd, bd, md, vd, t1, vbuf);
    kv2_kernel<<<dim3(8, 8), 256, 0, stream>>>(t1, wo2, go2, bo2, mo2, vo2, kbuf);
    pad_kernel<<<2048, 256, 0, stream>>>(kbuf, vbuf, ktb, vtb);

    // q1T = bn_relu(xT wp1^T) -> d_out low half
    gemm256<0, 1><<<1024, 512, 0, stream>>>(r0, wp1h, cons, cons + 512, q1T);
    // q2T = bn_relu(q1T wp2^T) -> r0
    gemm256<0, 1><<<1024, 512, 0, stream>>>(q1T, wp2h, cons + 1024, cons + 1536, r0);
    // fused attention: r0 (q2T) -> r0 (ctx)
    attn_fused<<<1024, 256, 0, stream>>>(r0, ktb, vtb, r0);
    // out = bn_relu(wu ctx) -> d_out fp32 NCHW
    gemm256<1, 1><<<1024, 512, 0, stream>>>(r0, wuh, cons + 2048, cons + 2560, outf);
}